// Round 1
// baseline (161.106 us; speedup 1.0000x reference)
//
#include <hip/hip_runtime.h>
#include <cstddef>

#define NB  4096
#define TT  200
#define DD  64
#define NH1 80
#define NH2 40

typedef _Float16 half8 __attribute__((ext_vector_type(8)));
typedef float    f32x4 __attribute__((ext_vector_type(4)));

// ---- workspace layout (bytes) ----
// wQh  [4096][80] f32 : q@(W1a+W1c) + b1
// wWB  [80][128]  f16 : row h, cols 0..63 = (W1b-W1c)^T, 64..127 = W1d^T
// wW2t [48][128]  f16 : row n, cols k<80 = W2[k][n], rest 0
static const size_t OFF_QH  = 0;
static const size_t OFF_WB  = (size_t)NB * NH1 * 4;
static const size_t OFF_W2T = OFF_WB + (size_t)80 * 128 * 2;

__global__ void prep_weights(const float* __restrict__ W1, const float* __restrict__ W2,
                             _Float16* __restrict__ wWB, _Float16* __restrict__ wW2t)
{
    const int tid = blockIdx.x * blockDim.x + threadIdx.x;
    const int stride = blockDim.x * gridDim.x;
    for (int i = tid; i < 80 * 128; i += stride) {
        const int h = i >> 7, kk = i & 127;
        float w;
        if (kk < 64) w = W1[(64 + kk) * NH1 + h] - W1[(128 + kk) * NH1 + h];
        else         w = W1[(128 + kk) * NH1 + h];   // 192 + (kk-64)
        wWB[i] = (_Float16)w;
    }
    for (int i = tid; i < 48 * 128; i += stride) {
        const int n = i >> 7, kk = i & 127;
        const float w = (n < NH2 && kk < NH1) ? W2[kk * NH2 + n] : 0.f;
        wW2t[i] = (_Float16)w;
    }
}

__global__ void prep_qh(const float* __restrict__ q, const float* __restrict__ W1,
                        const float* __restrict__ b1, float* __restrict__ wQh)
{
    const int idx = blockIdx.x * blockDim.x + threadIdx.x;
    if (idx >= NB * NH1) return;
    const int b = idx / NH1;
    const int h = idx - b * NH1;
    const float* qb = q + (size_t)b * DD;
    float acc = b1[h];
#pragma unroll 8
    for (int d = 0; d < DD; ++d)
        acc += qb[d] * (W1[d * NH1 + h] + W1[(128 + d) * NH1 + h]);
    wQh[idx] = acc;
}

__global__ __launch_bounds__(256, 2)
void attn_main(const float* __restrict__ q, const float* __restrict__ k,
               const float* __restrict__ v, const int* __restrict__ mask,
               const float* __restrict__ b2g, const float* __restrict__ Wf,
               const float* __restrict__ bf,
               const float* __restrict__ wQh, const _Float16* __restrict__ wWB,
               const _Float16* __restrict__ wW2t, float* __restrict__ out)
{
    __shared__ __align__(16) _Float16 sH1[208 * 128];   // swizzled: slot ^= row&7
    __shared__ float sQh[96];
    __shared__ float sWf[48];
    __shared__ float sB2[48];
    __shared__ float sLogit[208];
    __shared__ float sAttn[208];
    __shared__ float sRed[8];
    __shared__ float sVred[1024];

    const int b    = blockIdx.x;
    const int tid  = threadIdx.x;
    const int wid  = tid >> 6;
    const int lane = tid & 63;
    const int lr   = lane & 15;   // A-row / B-col / C-col within tile
    const int lg   = lane >> 4;   // K-group (A/B) / row-group (C)
    const float bfv = bf[0];

    if (tid < 96)                  sQh[tid]      = (tid < NH1) ? wQh[(size_t)b * NH1 + tid] : 0.f;
    if (tid >= 96  && tid < 144) { int c = tid - 96;  sWf[c] = (c < NH2) ? Wf[c]  : 0.f; }
    if (tid >= 144 && tid < 192) { int c = tid - 144; sB2[c] = (c < NH2) ? b2g[c] : 0.f; }

    // B fragments straight from global (L2-resident images)
    half8 bf1[5][4];
#pragma unroll
    for (int n = 0; n < 5; ++n)
#pragma unroll
        for (int s = 0; s < 4; ++s)
            bf1[n][s] = *(const half8*)(wWB + ((n * 16 + lr) * 128 + s * 32 + lg * 8));
    half8 bf2[3][3];
#pragma unroll
    for (int n = 0; n < 3; ++n)
#pragma unroll
        for (int s = 0; s < 3; ++s)
            bf2[n][s] = *(const half8*)(wW2t + ((n * 16 + lr) * 128 + s * 32 + lg * 8));

    float qreg[16];
    {
        const float* qb = q + (size_t)b * DD;
#pragma unroll
        for (int j = 0; j < 8; ++j) qreg[j]     = qb[lg * 8 + j];
#pragma unroll
        for (int j = 0; j < 8; ++j) qreg[8 + j] = qb[32 + lg * 8 + j];
    }

    // zero-pad sH1 logical cols 80..95 (slots 10,11), same swizzle
    const f32x4 z4 = {};
    for (int i = tid; i < 208 * 2; i += 256) {
        const int row = i >> 1;
        const int pslot = (10 + (i & 1)) ^ (row & 7);
        *(f32x4*)((char*)sH1 + row * 256 + pslot * 16) = z4;
    }

    __syncthreads();   // sQh/sWf/sB2 ready

    // ---------------- layer 1: [208 x 128] x [128 x 80] ----------------
    for (int mt = wid; mt < 13; mt += 4) {
        const int t = mt * 16 + lr;
        f32x4 kv0 = {}, kv1 = {}, kv2 = {}, kv3 = {};
        if (t < TT) {
            const float* krow = k + ((size_t)b * TT + t) * DD;
            kv0 = *(const f32x4*)(krow + lg * 8);
            kv1 = *(const f32x4*)(krow + lg * 8 + 4);
            kv2 = *(const f32x4*)(krow + 32 + lg * 8);
            kv3 = *(const f32x4*)(krow + 32 + lg * 8 + 4);
        }
        half8 af0, af1, af2, af3;
#pragma unroll
        for (int j = 0; j < 4; ++j) {
            af0[j] = (_Float16)kv0[j];                 af0[j + 4] = (_Float16)kv1[j];
            af1[j] = (_Float16)kv2[j];                 af1[j + 4] = (_Float16)kv3[j];
            af2[j] = (_Float16)(qreg[j]     * kv0[j]); af2[j + 4] = (_Float16)(qreg[j + 4]  * kv1[j]);
            af3[j] = (_Float16)(qreg[8 + j] * kv2[j]); af3[j + 4] = (_Float16)(qreg[12 + j] * kv3[j]);
        }
        f32x4 acc[5] = {};
#pragma unroll
        for (int n = 0; n < 5; ++n) {
            acc[n] = __builtin_amdgcn_mfma_f32_16x16x32_f16(af0, bf1[n][0], acc[n], 0, 0, 0);
            acc[n] = __builtin_amdgcn_mfma_f32_16x16x32_f16(af1, bf1[n][1], acc[n], 0, 0, 0);
            acc[n] = __builtin_amdgcn_mfma_f32_16x16x32_f16(af2, bf1[n][2], acc[n], 0, 0, 0);
            acc[n] = __builtin_amdgcn_mfma_f32_16x16x32_f16(af3, bf1[n][3], acc[n], 0, 0, 0);
        }
        // epilogue: h1 = relu(acc + qh[col]); swizzled f16 store
#pragma unroll
        for (int n = 0; n < 5; ++n) {
            const int hcol = n * 16 + lr;
            const float qh = sQh[hcol];
            const int slot   = (hcol * 2) >> 4;
            const int within = (hcol * 2) & 15;
#pragma unroll
            for (int j = 0; j < 4; ++j) {
                const int row = mt * 16 + lg * 4 + j;
                const float hv = fmaxf(acc[n][j] + qh, 0.f);
                *(_Float16*)((char*)sH1 + row * 256 + ((slot ^ (row & 7)) * 16) + within) = (_Float16)hv;
            }
        }
    }
    __syncthreads();

    // ---------------- layer 2: [208 x 96] x [96 x 48] + logit reduce ----------------
    for (int mt = wid; mt < 13; mt += 4) {
        const int row = mt * 16 + lr;
        half8 a2[3];
#pragma unroll
        for (int s = 0; s < 3; ++s) {
            const int pslot = (s * 4 + lg) ^ (row & 7);
            a2[s] = *(const half8*)((char*)sH1 + row * 256 + pslot * 16);
        }
        f32x4 acc2[3] = {};
#pragma unroll
        for (int n = 0; n < 3; ++n)
#pragma unroll
            for (int s = 0; s < 3; ++s)
                acc2[n] = __builtin_amdgcn_mfma_f32_16x16x32_f16(a2[s], bf2[n][s], acc2[n], 0, 0, 0);

        float p0 = 0.f, p1 = 0.f, p2 = 0.f, p3 = 0.f;
#pragma unroll
        for (int n = 0; n < 3; ++n) {
            const int hcol = n * 16 + lr;
            const float wf = sWf[hcol];
            const float bb = sB2[hcol];
            p0 += fmaxf(acc2[n][0] + bb, 0.f) * wf;
            p1 += fmaxf(acc2[n][1] + bb, 0.f) * wf;
            p2 += fmaxf(acc2[n][2] + bb, 0.f) * wf;
            p3 += fmaxf(acc2[n][3] + bb, 0.f) * wf;
        }
#pragma unroll
        for (int off = 1; off < 16; off <<= 1) {
            p0 += __shfl_xor(p0, off);
            p1 += __shfl_xor(p1, off);
            p2 += __shfl_xor(p2, off);
            p3 += __shfl_xor(p3, off);
        }
        if (lr == 0) {
            const int rbase = mt * 16 + lg * 4;
            sLogit[rbase + 0] = p0 + bfv;
            sLogit[rbase + 1] = p1 + bfv;
            sLogit[rbase + 2] = p2 + bfv;
            sLogit[rbase + 3] = p3 + bfv;
        }
    }
    __syncthreads();

    // ---------------- masked softmax over T ----------------
    {
        const int t = tid;
        float lgv = -3.0e38f;
        if (t < TT) lgv = (mask[(size_t)b * TT + t] != 0) ? sLogit[t] : -4294967295.0f;
        float m = lgv;
#pragma unroll
        for (int off = 32; off > 0; off >>= 1) m = fmaxf(m, __shfl_xor(m, off));
        if (lane == 0) sRed[wid] = m;
        __syncthreads();
        const float M = fmaxf(fmaxf(sRed[0], sRed[1]), fmaxf(sRed[2], sRed[3]));
        float e = (t < TT) ? __expf(lgv - M) : 0.f;
        float s = e;
#pragma unroll
        for (int off = 32; off > 0; off >>= 1) s += __shfl_xor(s, off);
        if (lane == 0) sRed[4 + wid] = s;
        __syncthreads();
        const float S = sRed[4] + sRed[5] + sRed[6] + sRed[7];
        if (t < TT) sAttn[t] = e / S;
    }
    __syncthreads();

    // ---------------- weighted sum over v ----------------
    {
        const int dq = (tid & 15) * 4;
        const int g  = tid >> 4;           // 16 t-groups
        const float* vb = v + (size_t)b * (TT * DD);
        f32x4 acc = {};
#pragma unroll
        for (int i = 0; i < 13; ++i) {
            const int t0 = g + i * 16;
            if (t0 < TT) {
                const f32x4 vv = *(const f32x4*)(vb + t0 * DD + dq);
                acc += vv * sAttn[t0];
            }
        }
        *(f32x4*)(&sVred[g * 64 + dq]) = acc;
    }
    __syncthreads();
    if (tid < 64) {
        float r = 0.f;
#pragma unroll
        for (int gg = 0; gg < 16; ++gg) r += sVred[gg * 64 + tid];
        out[(size_t)b * DD + tid] = r;
    }
}

extern "C" void kernel_launch(void* const* d_in, const int* in_sizes, int n_in,
                              void* d_out, int out_size, void* d_ws, size_t ws_size,
                              hipStream_t stream)
{
    const float* q   = (const float*)d_in[0];
    const float* k   = (const float*)d_in[1];
    const float* v   = (const float*)d_in[2];
    const int*  mask = (const int*)  d_in[3];
    const float* W1  = (const float*)d_in[4];
    const float* b1  = (const float*)d_in[5];
    const float* W2  = (const float*)d_in[6];
    const float* b2  = (const float*)d_in[7];
    const float* Wf  = (const float*)d_in[8];
    const float* bf  = (const float*)d_in[9];
    float* out = (float*)d_out;

    char* ws = (char*)d_ws;
    float*    wQh  = (float*)   (ws + OFF_QH);
    _Float16* wWB  = (_Float16*)(ws + OFF_WB);
    _Float16* wW2t = (_Float16*)(ws + OFF_W2T);

    prep_weights<<<16, 256, 0, stream>>>(W1, W2, wWB, wW2t);
    prep_qh<<<(NB * NH1 + 255) / 256, 256, 0, stream>>>(q, W1, b1, wQh);
    attn_main<<<NB, 256, 0, stream>>>(q, k, v, mask, b2, Wf, bf, wQh, wWB, wW2t, out);
}